// Round 1
// baseline (4030.080 us; speedup 1.0000x reference)
//
#include <hip/hip_runtime.h>
#include <math.h>

#define BB 64
#define TT 2048
#define II 256
#define HH 256
#define OO 128

// ---------------------------------------------------------------------------
// GEMM with bias: C[m,n] = sum_k A[m,k] * W[n,k] + b1[n] + b2[n]
// A: [M, 256] row-major, W: [N, 256] row-major, C: [M, N].
// Tile: BM=BN=128, BK=16; 256 threads; 8x8 microtile per thread.
// M must be a multiple of 128; N in {256, 128}.
// ---------------------------------------------------------------------------
template<int N>
__global__ __launch_bounds__(256)
void gemm_bias(const float* __restrict__ A, const float* __restrict__ W,
               const float* __restrict__ b1, const float* __restrict__ b2,
               float* __restrict__ C)
{
    constexpr int K = 256;
    __shared__ float sA[16][132];
    __shared__ float sB[16][132];
    const int tid  = threadIdx.x;
    const long row0 = (long)blockIdx.x * 128;
    const int  col0 = blockIdx.y * 128;

    const int tm = tid & 15;     // micro-tile row group (8 rows each)
    const int tn = tid >> 4;     // micro-tile col group (8 cols each)

    float acc[8][8];
#pragma unroll
    for (int i = 0; i < 8; ++i)
#pragma unroll
        for (int j = 0; j < 8; ++j) acc[i][j] = 0.f;

    // flat float4 load mapping: 128 rows x 16 k = 512 float4, 2 per thread
    const int f0  = tid;
    const int f1  = tid + 256;
    const int am0 = f0 >> 2, ak0 = (f0 & 3) * 4;
    const int am1 = f1 >> 2, ak1 = (f1 & 3) * 4;

    for (int kt = 0; kt < K; kt += 16) {
        float4 a0 = *(const float4*)&A[(row0 + am0) * K + kt + ak0];
        float4 a1 = *(const float4*)&A[(row0 + am1) * K + kt + ak1];
        float4 w0 = *(const float4*)&W[(long)(col0 + am0) * K + kt + ak0];
        float4 w1 = *(const float4*)&W[(long)(col0 + am1) * K + kt + ak1];
        __syncthreads();   // previous compute must finish before overwrite
        sA[ak0+0][am0] = a0.x; sA[ak0+1][am0] = a0.y; sA[ak0+2][am0] = a0.z; sA[ak0+3][am0] = a0.w;
        sA[ak1+0][am1] = a1.x; sA[ak1+1][am1] = a1.y; sA[ak1+2][am1] = a1.z; sA[ak1+3][am1] = a1.w;
        sB[ak0+0][am0] = w0.x; sB[ak0+1][am0] = w0.y; sB[ak0+2][am0] = w0.z; sB[ak0+3][am0] = w0.w;
        sB[ak1+0][am1] = w1.x; sB[ak1+1][am1] = w1.y; sB[ak1+2][am1] = w1.z; sB[ak1+3][am1] = w1.w;
        __syncthreads();
#pragma unroll
        for (int k = 0; k < 16; ++k) {
            float4 av0 = *(const float4*)&sA[k][tm * 8];
            float4 av1 = *(const float4*)&sA[k][tm * 8 + 4];
            float4 bv0 = *(const float4*)&sB[k][tn * 8];
            float4 bv1 = *(const float4*)&sB[k][tn * 8 + 4];
            float am[8] = {av0.x, av0.y, av0.z, av0.w, av1.x, av1.y, av1.z, av1.w};
            float bn[8] = {bv0.x, bv0.y, bv0.z, bv0.w, bv1.x, bv1.y, bv1.z, bv1.w};
#pragma unroll
            for (int i = 0; i < 8; ++i)
#pragma unroll
                for (int j = 0; j < 8; ++j)
                    acc[i][j] += am[i] * bn[j];
        }
    }

    // epilogue: add bias, store
    float bias[8];
#pragma unroll
    for (int j = 0; j < 8; ++j) {
        int col = col0 + tn * 8 + j;
        bias[j] = b1[col] + b2[col];
    }
#pragma unroll
    for (int i = 0; i < 8; ++i) {
        long row = row0 + tm * 8 + i;
        float4 v0, v1;
        v0.x = acc[i][0] + bias[0]; v0.y = acc[i][1] + bias[1];
        v0.z = acc[i][2] + bias[2]; v0.w = acc[i][3] + bias[3];
        v1.x = acc[i][4] + bias[4]; v1.y = acc[i][5] + bias[5];
        v1.z = acc[i][6] + bias[6]; v1.w = acc[i][7] + bias[7];
        *(float4*)&C[row * N + col0 + tn * 8]     = v0;
        *(float4*)&C[row * N + col0 + tn * 8 + 4] = v1;
    }
}

// ---------------------------------------------------------------------------
// Layer-1 recurrence. One workgroup per batch (64 WGs x 1024 threads).
// XH: [B*T, 256]; in: xp1 (pre-activation incl. bias); out: h1 (in place).
// Thread (hout = tid&255, ks = tid>>8) holds W_hh1[hout, ks*64 .. ks*64+63]
// in 64 VGPRs. h state lives in LDS; all lanes of a wave read the same LDS
// addresses (broadcast, conflict-free).
// ---------------------------------------------------------------------------
__global__ __launch_bounds__(1024)
void rec1_kernel(const float* __restrict__ W_hh, float* __restrict__ XH)
{
    const int b    = blockIdx.x;
    const int tid  = threadIdx.x;
    const int hout = tid & 255;
    const int ks   = tid >> 8;          // 0..3

    __shared__ float h_lds[256];
    __shared__ float part[1024];

    float4 w[16];
    const float4* wp = (const float4*)&W_hh[hout * 256 + ks * 64];
#pragma unroll
    for (int j = 0; j < 16; ++j) w[j] = wp[j];

    float* rowp = XH + (long)b * TT * HH;
    float xp = 0.f;
    if (tid < 256) {
        h_lds[tid] = 0.f;
        xp = rowp[tid];                  // xp for t=0
    }
    __syncthreads();

    for (int t = 0; t < TT; ++t) {
        const float4* hv = (const float4*)&h_lds[ks * 64];
        float s0 = 0.f, s1 = 0.f, s2 = 0.f, s3 = 0.f;
#pragma unroll
        for (int j = 0; j < 16; ++j) {
            float4 h4 = hv[j];
            s0 += w[j].x * h4.x;
            s1 += w[j].y * h4.y;
            s2 += w[j].z * h4.z;
            s3 += w[j].w * h4.w;
        }
        part[tid] = (s0 + s1) + (s2 + s3);
        __syncthreads();
        if (tid < 256) {
            float v = part[tid] + part[tid + 256] + part[tid + 512] + part[tid + 768] + xp;
            v = tanhf(v);
            h_lds[tid] = v;
            rowp[(long)t * HH + tid] = v;
            if (t + 1 < TT) xp = rowp[(long)(t + 1) * HH + tid];  // prefetch
        }
        __syncthreads();
    }
}

// ---------------------------------------------------------------------------
// Layer-2 recurrence. Same structure; O=128, K=128, 8-way k-split.
// XO: [B*T, 128]; in: xp2; out: final output (in place, row consumed before
// being overwritten).
// ---------------------------------------------------------------------------
__global__ __launch_bounds__(1024)
void rec2_kernel(const float* __restrict__ W_hh, float* __restrict__ XO)
{
    const int b    = blockIdx.x;
    const int tid  = threadIdx.x;
    const int oout = tid & 127;
    const int ks   = tid >> 7;          // 0..7

    __shared__ float o_lds[128];
    __shared__ float part[1024];

    float4 w[4];
    const float4* wp = (const float4*)&W_hh[oout * 128 + ks * 16];
#pragma unroll
    for (int j = 0; j < 4; ++j) w[j] = wp[j];

    float* rowp = XO + (long)b * TT * OO;
    float xp = 0.f;
    if (tid < 128) {
        o_lds[tid] = 0.f;
        xp = rowp[tid];                  // xp for t=0
    }
    __syncthreads();

    for (int t = 0; t < TT; ++t) {
        const float4* ov = (const float4*)&o_lds[ks * 16];
        float s0 = 0.f, s1 = 0.f, s2 = 0.f, s3 = 0.f;
#pragma unroll
        for (int j = 0; j < 4; ++j) {
            float4 o4 = ov[j];
            s0 += w[j].x * o4.x;
            s1 += w[j].y * o4.y;
            s2 += w[j].z * o4.z;
            s3 += w[j].w * o4.w;
        }
        part[tid] = (s0 + s1) + (s2 + s3);
        __syncthreads();
        if (tid < 128) {
            float v = xp;
#pragma unroll
            for (int r = 0; r < 8; ++r) v += part[tid + 128 * r];
            v = tanhf(v);
            o_lds[tid] = v;
            rowp[(long)t * OO + tid] = v;
            if (t + 1 < TT) xp = rowp[(long)(t + 1) * OO + tid];
        }
        __syncthreads();
    }
}

// ---------------------------------------------------------------------------
extern "C" void kernel_launch(void* const* d_in, const int* in_sizes, int n_in,
                              void* d_out, int out_size, void* d_ws, size_t ws_size,
                              hipStream_t stream)
{
    const float* x     = (const float*)d_in[0];
    const float* W_ih1 = (const float*)d_in[1];
    const float* W_hh1 = (const float*)d_in[2];
    const float* b_ih1 = (const float*)d_in[3];
    const float* b_hh1 = (const float*)d_in[4];
    const float* W_ih2 = (const float*)d_in[5];
    const float* W_hh2 = (const float*)d_in[6];
    const float* b_ih2 = (const float*)d_in[7];
    const float* b_hh2 = (const float*)d_in[8];
    float* out = (float*)d_out;
    float* xp1 = (float*)d_ws;          // [B*T, 256] fp32 = 128 MiB

    const int M = BB * TT;              // 131072

    // Phase A: xp1 = x @ W_ih1^T + b_ih1 + b_hh1   -> ws
    dim3 gA(M / 128, HH / 128);         // (1024, 2)
    gemm_bias<HH><<<gA, 256, 0, stream>>>(x, W_ih1, b_ih1, b_hh1, xp1);

    // Phase B: layer-1 recurrence, h1 written in place over xp1
    rec1_kernel<<<BB, 1024, 0, stream>>>(W_hh1, xp1);

    // Phase C: xp2 = h1 @ W_ih2^T + b_ih2 + b_hh2  -> d_out (temp storage)
    dim3 gC(M / 128, OO / 128);         // (1024, 1)
    gemm_bias<OO><<<gC, 256, 0, stream>>>(xp1, W_ih2, b_ih2, b_hh2, out);

    // Phase D: layer-2 recurrence, final output in place over xp2
    rec2_kernel<<<BB, 1024, 0, stream>>>(W_hh2, out);
}

// Round 2
// 2530.732 us; speedup vs baseline: 1.5925x; 1.5925x over previous
//
#include <hip/hip_runtime.h>
#include <math.h>

#define BB 64
#define TT 2048
#define II 256
#define HH 256
#define OO 128

// ---------------------------------------------------------------------------
// GEMM with bias: C[m,n] = sum_k A[m,k] * W[n,k] + b1[n] + b2[n]
// A: [M, 256] row-major, W: [N, 256] row-major, C: [M, N].
// Tile: BM=BN=128, BK=16; 256 threads; 8x8 microtile per thread.
// ---------------------------------------------------------------------------
template<int N>
__global__ __launch_bounds__(256)
void gemm_bias(const float* __restrict__ A, const float* __restrict__ W,
               const float* __restrict__ b1, const float* __restrict__ b2,
               float* __restrict__ C)
{
    constexpr int K = 256;
    __shared__ float sA[16][132];
    __shared__ float sB[16][132];
    const int tid  = threadIdx.x;
    const long row0 = (long)blockIdx.x * 128;
    const int  col0 = blockIdx.y * 128;

    const int tm = tid & 15;
    const int tn = tid >> 4;

    float acc[8][8];
#pragma unroll
    for (int i = 0; i < 8; ++i)
#pragma unroll
        for (int j = 0; j < 8; ++j) acc[i][j] = 0.f;

    const int f0  = tid;
    const int f1  = tid + 256;
    const int am0 = f0 >> 2, ak0 = (f0 & 3) * 4;
    const int am1 = f1 >> 2, ak1 = (f1 & 3) * 4;

    for (int kt = 0; kt < K; kt += 16) {
        float4 a0 = *(const float4*)&A[(row0 + am0) * K + kt + ak0];
        float4 a1 = *(const float4*)&A[(row0 + am1) * K + kt + ak1];
        float4 w0 = *(const float4*)&W[(long)(col0 + am0) * K + kt + ak0];
        float4 w1 = *(const float4*)&W[(long)(col0 + am1) * K + kt + ak1];
        __syncthreads();
        sA[ak0+0][am0] = a0.x; sA[ak0+1][am0] = a0.y; sA[ak0+2][am0] = a0.z; sA[ak0+3][am0] = a0.w;
        sA[ak1+0][am1] = a1.x; sA[ak1+1][am1] = a1.y; sA[ak1+2][am1] = a1.z; sA[ak1+3][am1] = a1.w;
        sB[ak0+0][am0] = w0.x; sB[ak0+1][am0] = w0.y; sB[ak0+2][am0] = w0.z; sB[ak0+3][am0] = w0.w;
        sB[ak1+0][am1] = w1.x; sB[ak1+1][am1] = w1.y; sB[ak1+2][am1] = w1.z; sB[ak1+3][am1] = w1.w;
        __syncthreads();
#pragma unroll
        for (int k = 0; k < 16; ++k) {
            float4 av0 = *(const float4*)&sA[k][tm * 8];
            float4 av1 = *(const float4*)&sA[k][tm * 8 + 4];
            float4 bv0 = *(const float4*)&sB[k][tn * 8];
            float4 bv1 = *(const float4*)&sB[k][tn * 8 + 4];
            float am[8] = {av0.x, av0.y, av0.z, av0.w, av1.x, av1.y, av1.z, av1.w};
            float bn[8] = {bv0.x, bv0.y, bv0.z, bv0.w, bv1.x, bv1.y, bv1.z, bv1.w};
#pragma unroll
            for (int i = 0; i < 8; ++i)
#pragma unroll
                for (int j = 0; j < 8; ++j)
                    acc[i][j] += am[i] * bn[j];
        }
    }

    float bias[8];
#pragma unroll
    for (int j = 0; j < 8; ++j) {
        int col = col0 + tn * 8 + j;
        bias[j] = b1[col] + b2[col];
    }
#pragma unroll
    for (int i = 0; i < 8; ++i) {
        long row = row0 + tm * 8 + i;
        float4 v0, v1;
        v0.x = acc[i][0] + bias[0]; v0.y = acc[i][1] + bias[1];
        v0.z = acc[i][2] + bias[2]; v0.w = acc[i][3] + bias[3];
        v1.x = acc[i][4] + bias[4]; v1.y = acc[i][5] + bias[5];
        v1.z = acc[i][6] + bias[6]; v1.w = acc[i][7] + bias[7];
        *(float4*)&C[row * N + col0 + tn * 8]     = v0;
        *(float4*)&C[row * N + col0 + tn * 8 + 4] = v1;
    }
}

__device__ __forceinline__ float fast_tanh(float x) {
    // 1 - 2/(e^{2x}+1): correct limits at +/-inf, ~1e-7 abs error
    float e = __expf(2.f * x);
    return 1.f - 2.f / (e + 1.f);
}

// ---------------------------------------------------------------------------
// Layer-1 recurrence, register-blocked. One WG per batch: 64 WGs x 512 thr.
// Thread (g = tid&31, ks = tid>>5) owns rows [g*8, g*8+8) x k-slice
// [ks*16, ks*16+16): 32 float4 of W_hh in registers (launch_bounds(512,2)
// gives a 256-VGPR budget so the compiler keeps them resident).
// Per step: broadcast-read 16 h floats (4 x b128, conflict-free), 128 fmacs,
// write 8 partials (2 x b128), barrier, 256 finalists reduce 16 partials +
// tanh + store, barrier.  LDS-port cost ~1000 cyc/step vs 2950 before.
// ---------------------------------------------------------------------------
__global__ __launch_bounds__(512, 2)
void rec1_kernel(const float* __restrict__ W_hh, float* __restrict__ XH)
{
    const int b   = blockIdx.x;
    const int tid = threadIdx.x;
    const int g   = tid & 31;    // row group: rows g*8 .. g*8+7
    const int ks  = tid >> 5;    // 0..15, k-slice [ks*16, +16)

    __shared__ float h_lds[256];
    __shared__ float part[16 * 256];

    float4 w[8][4];
#pragma unroll
    for (int r = 0; r < 8; ++r)
#pragma unroll
        for (int c = 0; c < 4; ++c)
            w[r][c] = *(const float4*)&W_hh[(g * 8 + r) * 256 + ks * 16 + c * 4];

    float* rowp = XH + (long)b * TT * HH;
    float xp = 0.f;
    if (tid < 256) {
        h_lds[tid] = 0.f;
        xp = rowp[tid];                       // xp for t=0
    }
    __syncthreads();

    for (int t = 0; t < TT; ++t) {
        float4 h4[4];
#pragma unroll
        for (int c = 0; c < 4; ++c)
            h4[c] = *(const float4*)&h_lds[ks * 16 + c * 4];

        float acc[8];
#pragma unroll
        for (int r = 0; r < 8; ++r) acc[r] = 0.f;
#pragma unroll
        for (int c = 0; c < 4; ++c)
#pragma unroll
            for (int r = 0; r < 8; ++r)
                acc[r] += w[r][c].x * h4[c].x + w[r][c].y * h4[c].y
                        + w[r][c].z * h4[c].z + w[r][c].w * h4[c].w;

        float4 p0 = make_float4(acc[0], acc[1], acc[2], acc[3]);
        float4 p1 = make_float4(acc[4], acc[5], acc[6], acc[7]);
        *(float4*)&part[ks * 256 + g * 8]     = p0;
        *(float4*)&part[ks * 256 + g * 8 + 4] = p1;
        __syncthreads();

        if (tid < 256) {
            float s0 = part[0 * 256 + tid] + part[1 * 256 + tid]
                     + part[2 * 256 + tid] + part[3 * 256 + tid];
            float s1 = part[4 * 256 + tid] + part[5 * 256 + tid]
                     + part[6 * 256 + tid] + part[7 * 256 + tid];
            float s2 = part[8 * 256 + tid] + part[9 * 256 + tid]
                     + part[10 * 256 + tid] + part[11 * 256 + tid];
            float s3 = part[12 * 256 + tid] + part[13 * 256 + tid]
                     + part[14 * 256 + tid] + part[15 * 256 + tid];
            float v = fast_tanh(((s0 + s1) + (s2 + s3)) + xp);
            h_lds[tid] = v;
            rowp[(long)t * HH + tid] = v;
            if (t + 1 < TT) xp = rowp[(long)(t + 1) * HH + tid];   // prefetch
        }
        __syncthreads();
    }
}

// ---------------------------------------------------------------------------
// Layer-2 recurrence, register-blocked. 64 WGs x 256 thr.
// Thread (g = tid&31, ks = tid>>5) owns rows [g*4, g*4+4) x k-slice
// [ks*16, +16): 16 float4 of W_hh2 in registers.
// ---------------------------------------------------------------------------
__global__ __launch_bounds__(256, 2)
void rec2_kernel(const float* __restrict__ W_hh, float* __restrict__ XO)
{
    const int b   = blockIdx.x;
    const int tid = threadIdx.x;
    const int g   = tid & 31;    // row group: rows g*4 .. g*4+3
    const int ks  = tid >> 5;    // 0..7, k-slice [ks*16, +16)

    __shared__ float h_lds[128];
    __shared__ float part[8 * 128];

    float4 w[4][4];
#pragma unroll
    for (int r = 0; r < 4; ++r)
#pragma unroll
        for (int c = 0; c < 4; ++c)
            w[r][c] = *(const float4*)&W_hh[(g * 4 + r) * 128 + ks * 16 + c * 4];

    float* rowp = XO + (long)b * TT * OO;
    float xp = 0.f;
    if (tid < 128) {
        h_lds[tid] = 0.f;
        xp = rowp[tid];                       // xp for t=0
    }
    __syncthreads();

    for (int t = 0; t < TT; ++t) {
        float4 h4[4];
#pragma unroll
        for (int c = 0; c < 4; ++c)
            h4[c] = *(const float4*)&h_lds[ks * 16 + c * 4];

        float acc[4];
#pragma unroll
        for (int r = 0; r < 4; ++r) acc[r] = 0.f;
#pragma unroll
        for (int c = 0; c < 4; ++c)
#pragma unroll
            for (int r = 0; r < 4; ++r)
                acc[r] += w[r][c].x * h4[c].x + w[r][c].y * h4[c].y
                        + w[r][c].z * h4[c].z + w[r][c].w * h4[c].w;

        *(float4*)&part[ks * 128 + g * 4] = make_float4(acc[0], acc[1], acc[2], acc[3]);
        __syncthreads();

        if (tid < 128) {
            float s0 = part[0 * 128 + tid] + part[1 * 128 + tid]
                     + part[2 * 128 + tid] + part[3 * 128 + tid];
            float s1 = part[4 * 128 + tid] + part[5 * 128 + tid]
                     + part[6 * 128 + tid] + part[7 * 128 + tid];
            float v = fast_tanh((s0 + s1) + xp);
            h_lds[tid] = v;
            rowp[(long)t * OO + tid] = v;
            if (t + 1 < TT) xp = rowp[(long)(t + 1) * OO + tid];   // prefetch
        }
        __syncthreads();
    }
}

// ---------------------------------------------------------------------------
extern "C" void kernel_launch(void* const* d_in, const int* in_sizes, int n_in,
                              void* d_out, int out_size, void* d_ws, size_t ws_size,
                              hipStream_t stream)
{
    const float* x     = (const float*)d_in[0];
    const float* W_ih1 = (const float*)d_in[1];
    const float* W_hh1 = (const float*)d_in[2];
    const float* b_ih1 = (const float*)d_in[3];
    const float* b_hh1 = (const float*)d_in[4];
    const float* W_ih2 = (const float*)d_in[5];
    const float* W_hh2 = (const float*)d_in[6];
    const float* b_ih2 = (const float*)d_in[7];
    const float* b_hh2 = (const float*)d_in[8];
    float* out = (float*)d_out;
    float* xp1 = (float*)d_ws;          // [B*T, 256] fp32 = 128 MiB

    const int M = BB * TT;              // 131072

    // Phase A: xp1 = x @ W_ih1^T + b_ih1 + b_hh1   -> ws
    dim3 gA(M / 128, HH / 128);
    gemm_bias<HH><<<gA, 256, 0, stream>>>(x, W_ih1, b_ih1, b_hh1, xp1);

    // Phase B: layer-1 recurrence, h1 written in place over xp1
    rec1_kernel<<<BB, 512, 0, stream>>>(W_hh1, xp1);

    // Phase C: xp2 = h1 @ W_ih2^T + b_ih2 + b_hh2  -> d_out (temp storage)
    dim3 gC(M / 128, OO / 128);
    gemm_bias<OO><<<gC, 256, 0, stream>>>(xp1, W_ih2, b_ih2, b_hh2, out);

    // Phase D: layer-2 recurrence, final output in place over xp2
    rec2_kernel<<<BB, 256, 0, stream>>>(W_hh2, out);
}

// Round 3
// 2066.006 us; speedup vs baseline: 1.9507x; 1.2249x over previous
//
#include <hip/hip_runtime.h>
#include <math.h>

#define BB 64
#define TT 2048
#define II 256
#define HH 256
#define OO 128

// ---------------------------------------------------------------------------
// GEMM with bias: C[m,n] = sum_k A[m,k] * W[n,k] + b1[n] + b2[n]
// (unchanged from round 2; only used for xp1 now)
// ---------------------------------------------------------------------------
template<int N>
__global__ __launch_bounds__(256)
void gemm_bias(const float* __restrict__ A, const float* __restrict__ W,
               const float* __restrict__ b1, const float* __restrict__ b2,
               float* __restrict__ C)
{
    constexpr int K = 256;
    __shared__ float sA[16][132];
    __shared__ float sB[16][132];
    const int tid  = threadIdx.x;
    const long row0 = (long)blockIdx.x * 128;
    const int  col0 = blockIdx.y * 128;

    const int tm = tid & 15;
    const int tn = tid >> 4;

    float acc[8][8];
#pragma unroll
    for (int i = 0; i < 8; ++i)
#pragma unroll
        for (int j = 0; j < 8; ++j) acc[i][j] = 0.f;

    const int f0  = tid;
    const int f1  = tid + 256;
    const int am0 = f0 >> 2, ak0 = (f0 & 3) * 4;
    const int am1 = f1 >> 2, ak1 = (f1 & 3) * 4;

    for (int kt = 0; kt < K; kt += 16) {
        float4 a0 = *(const float4*)&A[(row0 + am0) * K + kt + ak0];
        float4 a1 = *(const float4*)&A[(row0 + am1) * K + kt + ak1];
        float4 w0 = *(const float4*)&W[(long)(col0 + am0) * K + kt + ak0];
        float4 w1 = *(const float4*)&W[(long)(col0 + am1) * K + kt + ak1];
        __syncthreads();
        sA[ak0+0][am0] = a0.x; sA[ak0+1][am0] = a0.y; sA[ak0+2][am0] = a0.z; sA[ak0+3][am0] = a0.w;
        sA[ak1+0][am1] = a1.x; sA[ak1+1][am1] = a1.y; sA[ak1+2][am1] = a1.z; sA[ak1+3][am1] = a1.w;
        sB[ak0+0][am0] = w0.x; sB[ak0+1][am0] = w0.y; sB[ak0+2][am0] = w0.z; sB[ak0+3][am0] = w0.w;
        sB[ak1+0][am1] = w1.x; sB[ak1+1][am1] = w1.y; sB[ak1+2][am1] = w1.z; sB[ak1+3][am1] = w1.w;
        __syncthreads();
#pragma unroll
        for (int k = 0; k < 16; ++k) {
            float4 av0 = *(const float4*)&sA[k][tm * 8];
            float4 av1 = *(const float4*)&sA[k][tm * 8 + 4];
            float4 bv0 = *(const float4*)&sB[k][tn * 8];
            float4 bv1 = *(const float4*)&sB[k][tn * 8 + 4];
            float am[8] = {av0.x, av0.y, av0.z, av0.w, av1.x, av1.y, av1.z, av1.w};
            float bn[8] = {bv0.x, bv0.y, bv0.z, bv0.w, bv1.x, bv1.y, bv1.z, bv1.w};
#pragma unroll
            for (int i = 0; i < 8; ++i)
#pragma unroll
                for (int j = 0; j < 8; ++j)
                    acc[i][j] += am[i] * bn[j];
        }
    }

    float bias[8];
#pragma unroll
    for (int j = 0; j < 8; ++j) {
        int col = col0 + tn * 8 + j;
        bias[j] = b1[col] + b2[col];
    }
#pragma unroll
    for (int i = 0; i < 8; ++i) {
        long row = row0 + tm * 8 + i;
        float4 v0, v1;
        v0.x = acc[i][0] + bias[0]; v0.y = acc[i][1] + bias[1];
        v0.z = acc[i][2] + bias[2]; v0.w = acc[i][3] + bias[3];
        v1.x = acc[i][4] + bias[4]; v1.y = acc[i][5] + bias[5];
        v1.z = acc[i][6] + bias[6]; v1.w = acc[i][7] + bias[7];
        *(float4*)&C[row * N + col0 + tn * 8]     = v0;
        *(float4*)&C[row * N + col0 + tn * 8 + 4] = v1;
    }
}

__device__ __forceinline__ float fast_tanh(float x) {
    // 1 - 2/(e^{2x}+1): correct limits at +/-inf, ~1e-7 abs error
    float e = __expf(2.f * x);
    return 1.f - 2.f / (e + 1.f);
}

// ---------------------------------------------------------------------------
// Pipelined RNN: 128 WGs x 512 threads, all co-resident on 256 CUs.
//   WG b in [0,64):    producer — layer-1 recurrence for batch b (round-2
//                      rec1 body). Writes h1_t in place over xp1, releases
//                      flags[b]=t+1 every 4 steps (agent scope: wbl2 pushes
//                      the rows to the L3 coherence point).
//   WG b+64:           consumer — computes o_t = tanh(W_ih2 h1_t + b + W_hh2
//                      o_{t-1}) for batch b, trailing the producer via the
//                      flag. W_ih2/W_hh2 slices register-resident (96 f/thr).
// Consumer per-step ~1200 cyc < producer ~1580 -> fully hidden.
// ---------------------------------------------------------------------------
__global__ __launch_bounds__(512, 2)
void rnn_pipe(const float* __restrict__ W_hh1,
              const float* __restrict__ W_ih2,
              const float* __restrict__ W_hh2,
              const float* __restrict__ b_ih2,
              const float* __restrict__ b_hh2,
              float* __restrict__ XH,          // xp1 in / h1 out (in place)
              float* __restrict__ out,         // [B*T, OO]
              int* __restrict__ flags)         // [BB], pre-zeroed
{
    const int tid = threadIdx.x;
    const int g   = tid & 31;
    const int ks  = tid >> 5;

    if (blockIdx.x < BB) {
        // ------------------------- producer -------------------------------
        __shared__ float h_lds[256];
        __shared__ float part[16 * 256];
        const int b = blockIdx.x;

        float4 w[8][4];
#pragma unroll
        for (int r = 0; r < 8; ++r)
#pragma unroll
            for (int c = 0; c < 4; ++c)
                w[r][c] = *(const float4*)&W_hh1[(g * 8 + r) * 256 + ks * 16 + c * 4];

        float* rowp = XH + (long)b * TT * HH;
        float xp = 0.f;
        if (tid < 256) {
            h_lds[tid] = 0.f;
            xp = rowp[tid];
        }
        __syncthreads();

        for (int t = 0; t < TT; ++t) {
            float4 h4[4];
#pragma unroll
            for (int c = 0; c < 4; ++c)
                h4[c] = *(const float4*)&h_lds[ks * 16 + c * 4];

            float acc[8];
#pragma unroll
            for (int r = 0; r < 8; ++r) acc[r] = 0.f;
#pragma unroll
            for (int c = 0; c < 4; ++c)
#pragma unroll
                for (int r = 0; r < 8; ++r)
                    acc[r] += w[r][c].x * h4[c].x + w[r][c].y * h4[c].y
                            + w[r][c].z * h4[c].z + w[r][c].w * h4[c].w;

            *(float4*)&part[ks * 256 + g * 8]     = make_float4(acc[0], acc[1], acc[2], acc[3]);
            *(float4*)&part[ks * 256 + g * 8 + 4] = make_float4(acc[4], acc[5], acc[6], acc[7]);
            __syncthreads();

            if (tid < 256) {
                float s0 = part[0 * 256 + tid] + part[1 * 256 + tid]
                         + part[2 * 256 + tid] + part[3 * 256 + tid];
                float s1 = part[4 * 256 + tid] + part[5 * 256 + tid]
                         + part[6 * 256 + tid] + part[7 * 256 + tid];
                float s2 = part[8 * 256 + tid] + part[9 * 256 + tid]
                         + part[10 * 256 + tid] + part[11 * 256 + tid];
                float s3 = part[12 * 256 + tid] + part[13 * 256 + tid]
                         + part[14 * 256 + tid] + part[15 * 256 + tid];
                float v = fast_tanh(((s0 + s1) + (s2 + s3)) + xp);
                h_lds[tid] = v;
                rowp[(long)t * HH + tid] = v;
                if (t + 1 < TT) xp = rowp[(long)(t + 1) * HH + tid];
            }
            __syncthreads();

            // publish progress every 4 steps (store ordered after the
            // barrier's vmcnt drain; release@agent writes L2 back to L3)
            if ((t & 3) == 3 && tid == 0)
                __hip_atomic_store(&flags[b], t + 1, __ATOMIC_RELEASE,
                                   __HIP_MEMORY_SCOPE_AGENT);
        }
    } else {
        // ------------------------- consumer -------------------------------
        __shared__ float h1_lds[256];
        __shared__ float o_lds[128];
        __shared__ float part2[16 * 132];
        const int b = blockIdx.x - BB;

        // W_ih2 rows g*4..+3, k-slice ks*16..+15 ; W_hh2 same rows, ks*8..+7
        float4 wi[4][4];
        float4 wh[4][2];
#pragma unroll
        for (int r = 0; r < 4; ++r) {
#pragma unroll
            for (int c = 0; c < 4; ++c)
                wi[r][c] = *(const float4*)&W_ih2[(g * 4 + r) * 256 + ks * 16 + c * 4];
#pragma unroll
            for (int c = 0; c < 2; ++c)
                wh[r][c] = *(const float4*)&W_hh2[(g * 4 + r) * 128 + ks * 8 + c * 4];
        }

        float bias = 0.f;
        if (tid < 128) {
            bias = b_ih2[tid] + b_hh2[tid];
            o_lds[tid] = 0.f;
        }
        const float* h1p = XH + (long)b * TT * HH;
        float* outp      = out + (long)b * TT * OO;
        __syncthreads();

        int seen = 0;
        for (int t = 0; t < TT; ++t) {
            if (seen <= t) {
                do {
                    seen = __hip_atomic_load(&flags[b], __ATOMIC_ACQUIRE,
                                             __HIP_MEMORY_SCOPE_AGENT);
                } while (seen <= t);
            }
            // stage h1_t into LDS (1 KB, 64 lanes x float4)
            if (tid < 64)
                *(float4*)&h1_lds[tid * 4] = *(const float4*)&h1p[(long)t * HH + tid * 4];
            __syncthreads();

            float4 h4[4];
#pragma unroll
            for (int c = 0; c < 4; ++c)
                h4[c] = *(const float4*)&h1_lds[ks * 16 + c * 4];
            float4 o4[2];
#pragma unroll
            for (int c = 0; c < 2; ++c)
                o4[c] = *(const float4*)&o_lds[ks * 8 + c * 4];

            float acc[4];
#pragma unroll
            for (int r = 0; r < 4; ++r) acc[r] = 0.f;
#pragma unroll
            for (int c = 0; c < 4; ++c)
#pragma unroll
                for (int r = 0; r < 4; ++r)
                    acc[r] += wi[r][c].x * h4[c].x + wi[r][c].y * h4[c].y
                            + wi[r][c].z * h4[c].z + wi[r][c].w * h4[c].w;
#pragma unroll
            for (int c = 0; c < 2; ++c)
#pragma unroll
                for (int r = 0; r < 4; ++r)
                    acc[r] += wh[r][c].x * o4[c].x + wh[r][c].y * o4[c].y
                            + wh[r][c].z * o4[c].z + wh[r][c].w * o4[c].w;

            *(float4*)&part2[ks * 132 + g * 4] = make_float4(acc[0], acc[1], acc[2], acc[3]);
            __syncthreads();

            if (tid < 128) {
                float s = bias;
#pragma unroll
                for (int s16 = 0; s16 < 16; ++s16)
                    s += part2[s16 * 132 + tid];
                float v = fast_tanh(s);
                o_lds[tid] = v;
                outp[(long)t * OO + tid] = v;
            }
            // o_lds / part2 reuse is fenced by the stage barrier at loop top
        }
    }
}

// ---------------------------------------------------------------------------
extern "C" void kernel_launch(void* const* d_in, const int* in_sizes, int n_in,
                              void* d_out, int out_size, void* d_ws, size_t ws_size,
                              hipStream_t stream)
{
    const float* x     = (const float*)d_in[0];
    const float* W_ih1 = (const float*)d_in[1];
    const float* W_hh1 = (const float*)d_in[2];
    const float* b_ih1 = (const float*)d_in[3];
    const float* b_hh1 = (const float*)d_in[4];
    const float* W_ih2 = (const float*)d_in[5];
    const float* W_hh2 = (const float*)d_in[6];
    const float* b_ih2 = (const float*)d_in[7];
    const float* b_hh2 = (const float*)d_in[8];
    float* out = (float*)d_out;

    float* xp1 = (float*)d_ws;                         // [B*T, 256] = 128 MiB
    const size_t FLAG_OFF = (size_t)BB * TT * HH * sizeof(float);
    int* flags = (int*)((char*)d_ws + FLAG_OFF);       // [64] ints

    const int M = BB * TT;                             // 131072

    // zero the progress flags (ws is poisoned 0xAA before every launch)
    hipMemsetAsync(flags, 0, BB * sizeof(int), stream);

    // Phase A: xp1 = x @ W_ih1^T + b_ih1 + b_hh1   -> ws
    dim3 gA(M / 128, HH / 128);
    gemm_bias<HH><<<gA, 256, 0, stream>>>(x, W_ih1, b_ih1, b_hh1, xp1);

    // Phase B: pipelined layer-1 recurrence (producers) + fused
    //          projection+layer-2 recurrence (consumers)
    rnn_pipe<<<2 * BB, 512, 0, stream>>>(W_hh1, W_ih2, W_hh2, b_ih2, b_hh2,
                                         xp1, out, flags);
}